// Round 10
// baseline (164.431 us; speedup 1.0000x reference)
//
#include <hip/hip_runtime.h>
#include <hip/hip_bf16.h>

typedef __attribute__((ext_vector_type(8))) short short8;   // 8 bf16 = 4 VGPR
typedef __attribute__((ext_vector_type(4))) float f32x4;

// Problem dims (fixed by reference)
constexpr int Bb = 8;
constexpr int Dd = 64;
constexpr int Tt = 8192;
constexpr int Kk = 1024;
constexpr int BT = Bb * Tt;            // 65536 rows
constexpr int NTOT = Bb * Dd * Tt;     // 4194304 elements

// Output layout (float32): [codes BT][quantized NTOT][loss 1]
constexpr int OUT_Q_OFF = BT;
constexpr int OUT_LOSS_OFF = BT + NTOT;

// Workspace layout (bytes)
constexpr size_t WS_CODES_OFF = 0;                        // int32[BT]      256KB
constexpr size_t WS_PREC_OFF  = (size_t)BT * 4;           // float[K]       4KB
constexpr size_t WS_PART_OFF  = WS_PREC_OFF + 4096;       // float[256]     1KB
constexpr size_t WS_EH_OFF    = WS_PART_OFF + 4096;       // bf16[K*D] x3
constexpr size_t WS_EM_OFF    = WS_EH_OFF + (size_t)Kk * Dd * 2;
constexpr size_t WS_EL_OFF    = WS_EM_OFF + (size_t)Kk * Dd * 2;

// ---- bf16 helpers (RNE, matches numpy/jax) ----
__device__ inline ushort rne_bf16(float v) {
    unsigned u = __float_as_uint(v);
    return (ushort)((u + 0x7FFFu + ((u >> 16) & 1u)) >> 16);
}
__device__ inline float bf16f(ushort h) { return __uint_as_float(((unsigned)h) << 16); }

// ---------------- Kernel PS: fused prec + 3-way bf16 split ----------------
// prec fmaf chain in the EXACT order of the previous prec_kernel (x,y,z,w per
// float4, ascending i) -> bit-identical values; split math unchanged.
__global__ void __launch_bounds__(256) prep_kernel(const float* __restrict__ cb,
                                                   float* __restrict__ prec,
                                                   ushort* __restrict__ eh,
                                                   ushort* __restrict__ em,
                                                   ushort* __restrict__ el) {
    const int k = blockIdx.x * 256 + threadIdx.x;   // grid = 4 blocks -> k in [0,1024)
    const float4* row = reinterpret_cast<const float4*>(cb + (size_t)k * Dd);
    float4 v[16];
    float s = 0.f;
#pragma unroll
    for (int i = 0; i < 16; ++i) {
        v[i] = row[i];
        s = fmaf(v[i].x, v[i].x, s); s = fmaf(v[i].y, v[i].y, s);
        s = fmaf(v[i].z, v[i].z, s); s = fmaf(v[i].w, v[i].w, s);
    }
    prec[k] = s;
#pragma unroll
    for (int g = 0; g < 8; ++g) {   // 8 elems per group from v[2g], v[2g+1]
        float vals[8] = {v[2*g].x, v[2*g].y, v[2*g].z, v[2*g].w,
                         v[2*g+1].x, v[2*g+1].y, v[2*g+1].z, v[2*g+1].w};
        short8 hv, mv, lv;
#pragma unroll
        for (int j = 0; j < 8; ++j) {
            float x = vals[j];
            ushort h = rne_bf16(x);  float hf = bf16f(h);
            float r1 = x - hf;       ushort m = rne_bf16(r1); float mf = bf16f(m);
            float r2 = r1 - mf;      ushort l = rne_bf16(r2);
            hv[j] = (short)h; mv[j] = (short)m; lv[j] = (short)l;
        }
        const size_t base = (size_t)k * 64 + g * 8;
        *reinterpret_cast<short8*>(eh + base) = hv;
        *reinterpret_cast<short8*>(em + base) = mv;
        *reinterpret_cast<short8*>(el + base) = lv;
    }
}

// ---------------- Kernel A: fused split-MFMA GEMM + argmin ----------------
// Numerics identical to rounds 8/9 (6-pass split MFMA, reference-order fp32
// score, tie -> lowest k). Round-9 counters: MfmaUtil 29 / VALUBusy 29 /
// Occupancy 20% (2 waves/SIMD from launch_bounds(256,2)) -> latency-bound,
// not issue-bound. True unified reg usage is ~170-200 (112 arch VGPR + AGPR
// overflow), so (256,4)=128 budget would spill; (256,3)~170 is the safe
// occupancy step: 3 waves/SIMD, +50% TLP.
constexpr int TM = 64;              // rows per block
constexpr int NKT = Kk / 64;        // 16 k-tiles

__global__ void __launch_bounds__(256, 3) mfma_argmin_kernel(
    const float* __restrict__ z,
    const ushort* __restrict__ eh, const ushort* __restrict__ em,
    const ushort* __restrict__ el,
    const float* __restrict__ prec, float* __restrict__ out,
    int* __restrict__ codes_i)
{
    // z tile, 3 planes, swizzled: [split][row][d], row stride 128B, byte ^= (row&7)<<4
    __shared__ __align__(16) ushort z_lds[3 * 64 * 64];   // 24 KB
    __shared__ float zsq_part[4][64];
    __shared__ float zsq_lds[64];
    __shared__ float red_v[4][64];
    __shared__ int   red_i[4][64];

    const int tid = threadIdx.x;
    const int lane = tid & 63;
    const int w = tid >> 6;                 // wave 0..3 -> k-slice w*16..+16
    const int row0 = blockIdx.x * TM;
    const int b = row0 >> 13;
    const int t0 = row0 & (Tt - 1);

    // ---- stage z: read [d][t] coalesced, 3-way split, write transposed+swizzled
    {
        const int tt = tid & 63;            // row within tile
        const int dg = tid >> 6;            // d-group: d = dg*16 .. +16
        const float* zp = z + (size_t)b * (Dd * Tt) + (size_t)(dg * 16) * Tt + (t0 + tt);
        float vals[16];
        float psum = 0.f;
#pragma unroll
        for (int i = 0; i < 16; ++i) {
            float v = zp[(size_t)i * Tt];
            vals[i] = v;
            psum = fmaf(v, v, psum);
        }
        zsq_part[dg][tt] = psum;
#pragma unroll
        for (int g = 0; g < 2; ++g) {
            short8 hv, mv, lv;
#pragma unroll
            for (int j = 0; j < 8; ++j) {
                float v = vals[g * 8 + j];
                ushort h = rne_bf16(v);  float hf = bf16f(h);
                float r1 = v - hf;       ushort m = rne_bf16(r1); float mf = bf16f(m);
                float r2 = r1 - mf;      ushort l = rne_bf16(r2);
                hv[j] = (short)h; mv[j] = (short)m; lv[j] = (short)l;
            }
            const int byte_in_row = dg * 32 + g * 16;     // d0*2
            const int sw = tt * 128 + (byte_in_row ^ ((tt & 7) << 4));
            *reinterpret_cast<short8*>((char*)z_lds + 0 * 8192 + sw) = hv;
            *reinterpret_cast<short8*>((char*)z_lds + 1 * 8192 + sw) = mv;
            *reinterpret_cast<short8*>((char*)z_lds + 2 * 8192 + sw) = lv;
        }
    }
    __syncthreads();
    if (tid < 64)
        zsq_lds[tid] = ((zsq_part[0][tid] + zsq_part[1][tid]) + zsq_part[2][tid]) + zsq_part[3][tid];
    __syncthreads();

    // ---- A fragments into registers (once)
    short8 A[3][2][4];   // [plane][dstep][rf]
#pragma unroll
    for (int sA = 0; sA < 3; ++sA)
#pragma unroll
        for (int ds = 0; ds < 2; ++ds)
#pragma unroll
            for (int rf = 0; rf < 4; ++rf) {
                const int row = rf * 16 + (lane & 15);
                const int dby = ds * 64 + ((lane >> 4) * 16);
                A[sA][ds][rf] = *reinterpret_cast<const short8*>(
                    (char*)z_lds + sA * 8192 + row * 128 + (dby ^ ((row & 7) << 4)));
            }

    // per-lane row-set zsq: row = rf*16 + (lane>>4)*4 + j
    float zsq_r[16];
#pragma unroll
    for (int rf = 0; rf < 4; ++rf)
#pragma unroll
        for (int j = 0; j < 4; ++j)
            zsq_r[rf * 4 + j] = zsq_lds[rf * 16 + (lane >> 4) * 4 + j];

    float bestv[16];
    int   besti[16];
#pragma unroll
    for (int i = 0; i < 16; ++i) { bestv[i] = 3.4e38f; besti[i] = 0; }

    const int kl = lane & 15;
    const int d0 = (lane >> 4) * 8;

    short8 Bc[6];      // [p*2+ds]
    float esqc;
    {
        const size_t kg = (size_t)(w * 16 + kl);
        const size_t base = kg * 64 + d0;
        Bc[0] = *reinterpret_cast<const short8*>(eh + base);
        Bc[1] = *reinterpret_cast<const short8*>(eh + base + 32);
        Bc[2] = *reinterpret_cast<const short8*>(em + base);
        Bc[3] = *reinterpret_cast<const short8*>(em + base + 32);
        Bc[4] = *reinterpret_cast<const short8*>(el + base);
        Bc[5] = *reinterpret_cast<const short8*>(el + base + 32);
        esqc = prec[kg];
    }

    for (int kt = 0; kt < NKT; ++kt) {
        short8 Bn[6];
        float esqn = 0.f;
        if (kt + 1 < NKT) {
            const size_t kg = (size_t)((kt + 1) * 64 + w * 16 + kl);
            const size_t base = kg * 64 + d0;
            Bn[0] = *reinterpret_cast<const short8*>(eh + base);
            Bn[1] = *reinterpret_cast<const short8*>(eh + base + 32);
            Bn[2] = *reinterpret_cast<const short8*>(em + base);
            Bn[3] = *reinterpret_cast<const short8*>(em + base + 32);
            Bn[4] = *reinterpret_cast<const short8*>(el + base);
            Bn[5] = *reinterpret_cast<const short8*>(el + base + 32);
            esqn = prec[kg];
        }

        f32x4 acc[4];
#pragma unroll
        for (int rf = 0; rf < 4; ++rf) acc[rf] = (f32x4){0.f, 0.f, 0.f, 0.f};

        // pass order identical: per dstep: (zh,eh),(zh,em),(zh,el),(zm,eh),(zm,em),(zl,eh)
#pragma unroll
        for (int ds = 0; ds < 2; ++ds) {
#pragma unroll
            for (int rf = 0; rf < 4; ++rf)
                acc[rf] = __builtin_amdgcn_mfma_f32_16x16x32_bf16(A[0][ds][rf], Bc[0 * 2 + ds], acc[rf], 0, 0, 0);
#pragma unroll
            for (int rf = 0; rf < 4; ++rf)
                acc[rf] = __builtin_amdgcn_mfma_f32_16x16x32_bf16(A[0][ds][rf], Bc[1 * 2 + ds], acc[rf], 0, 0, 0);
#pragma unroll
            for (int rf = 0; rf < 4; ++rf)
                acc[rf] = __builtin_amdgcn_mfma_f32_16x16x32_bf16(A[0][ds][rf], Bc[2 * 2 + ds], acc[rf], 0, 0, 0);
#pragma unroll
            for (int rf = 0; rf < 4; ++rf)
                acc[rf] = __builtin_amdgcn_mfma_f32_16x16x32_bf16(A[1][ds][rf], Bc[0 * 2 + ds], acc[rf], 0, 0, 0);
#pragma unroll
            for (int rf = 0; rf < 4; ++rf)
                acc[rf] = __builtin_amdgcn_mfma_f32_16x16x32_bf16(A[1][ds][rf], Bc[1 * 2 + ds], acc[rf], 0, 0, 0);
#pragma unroll
            for (int rf = 0; rf < 4; ++rf)
                acc[rf] = __builtin_amdgcn_mfma_f32_16x16x32_bf16(A[2][ds][rf], Bc[0 * 2 + ds], acc[rf], 0, 0, 0);
        }

        // epilogue: score + running argmin (this lane's k = kglob for all 16 C-slots)
        const int kglob = kt * 64 + w * 16 + kl;
#pragma unroll
        for (int rf = 0; rf < 4; ++rf)
#pragma unroll
            for (int j = 0; j < 4; ++j) {
                const float t1 = zsq_r[rf * 4 + j] + esqc;       // round(zsq+esq)
                const float s = fmaf(-2.f, acc[rf][j], t1);      // round(t1-2dot)
                if (s < bestv[rf * 4 + j]) { bestv[rf * 4 + j] = s; besti[rf * 4 + j] = kglob; }
            }

        if (kt + 1 < NKT) {
#pragma unroll
            for (int i = 0; i < 6; ++i) Bc[i] = Bn[i];
            esqc = esqn;
        }
    }

    // ---- in-wave reduce over the 16 k-slots (lane&15) per row, tie -> lower k
#pragma unroll
    for (int i = 0; i < 16; ++i) {
#pragma unroll
        for (int m = 1; m < 16; m <<= 1) {
            const float ov = __shfl_xor(bestv[i], m, 16);
            const int   oi = __shfl_xor(besti[i], m, 16);
            if (ov < bestv[i] || (ov == bestv[i] && oi < besti[i])) {
                bestv[i] = ov; besti[i] = oi;
            }
        }
    }
    if ((lane & 15) == 0) {
#pragma unroll
        for (int rf = 0; rf < 4; ++rf)
#pragma unroll
            for (int j = 0; j < 4; ++j) {
                const int row = rf * 16 + (lane >> 4) * 4 + j;
                red_v[w][row] = bestv[rf * 4 + j];
                red_i[w][row] = besti[rf * 4 + j];
            }
    }
    __syncthreads();
    if (tid < 64) {
        float bv = red_v[0][tid];
        int   bi = red_i[0][tid];
#pragma unroll
        for (int s2 = 1; s2 < 4; ++s2) {
            const float v = red_v[s2][tid];
            const int   i = red_i[s2][tid];
            if (v < bv || (v == bv && i < bi)) { bv = v; bi = i; }
        }
        codes_i[row0 + tid] = bi;
        out[row0 + tid] = (float)bi;
    }
}

// ---------------- Kernel B: quantized + loss partials ----------------
__global__ void __launch_bounds__(256) quant_kernel(
    const float* __restrict__ z, const float* __restrict__ cb,
    const int* __restrict__ codes_i, float* __restrict__ out,
    float* __restrict__ partials)
{
    const int row = blockIdx.x * 256 + threadIdx.x;  // grid = 256 blocks
    const int b = row >> 13;
    const int t = row & (Tt - 1);
    const int code = codes_i[row];
    const float4* crow = reinterpret_cast<const float4*>(cb + (size_t)code * Dd);
    const float* zbase = z + (size_t)b * (Dd * Tt) + t;
    float* obase = out + OUT_Q_OFF + (size_t)b * (Dd * Tt) + t;

    float acc = 0.f;
#pragma unroll
    for (int d4 = 0; d4 < 16; ++d4) {
        float4 v = crow[d4];
        float vv[4] = {v.x, v.y, v.z, v.w};
#pragma unroll
        for (int j = 0; j < 4; ++j) {
            const int d = d4 * 4 + j;
            const float zv = zbase[(size_t)d * Tt];
            const float diff = vv[j] - zv;
            acc = fmaf(diff, diff, acc);
            obase[(size_t)d * Tt] = vv[j];
        }
    }

    __shared__ float red[256];
    red[threadIdx.x] = acc;
    __syncthreads();
#pragma unroll
    for (int s = 128; s > 0; s >>= 1) {
        if (threadIdx.x < s) red[threadIdx.x] += red[threadIdx.x + s];
        __syncthreads();
    }
    if (threadIdx.x == 0) partials[blockIdx.x] = red[0];
}

// ---------------- Kernel C: final loss reduce ----------------
__global__ void __launch_bounds__(256) loss_kernel(const float* __restrict__ partials,
                                                   float* __restrict__ out) {
    __shared__ float red[256];
    red[threadIdx.x] = partials[threadIdx.x];  // exactly 256 partials
    __syncthreads();
#pragma unroll
    for (int s = 128; s > 0; s >>= 1) {
        if (threadIdx.x < s) red[threadIdx.x] += red[threadIdx.x + s];
        __syncthreads();
    }
    if (threadIdx.x == 0)
        out[OUT_LOSS_OFF] = red[0] * (1.0f / (float)NTOT);
}

extern "C" void kernel_launch(void* const* d_in, const int* in_sizes, int n_in,
                              void* d_out, int out_size, void* d_ws, size_t ws_size,
                              hipStream_t stream) {
    const float* z = (const float*)d_in[0];
    const float* cb = (const float*)d_in[1];
    float* out = (float*)d_out;

    char* ws = (char*)d_ws;
    int* codes_i = (int*)(ws + WS_CODES_OFF);
    float* prec = (float*)(ws + WS_PREC_OFF);
    float* partials = (float*)(ws + WS_PART_OFF);
    ushort* eh = (ushort*)(ws + WS_EH_OFF);
    ushort* em = (ushort*)(ws + WS_EM_OFF);
    ushort* el = (ushort*)(ws + WS_EL_OFF);

    prep_kernel<<<Kk / 256, 256, 0, stream>>>(cb, prec, eh, em, el);
    mfma_argmin_kernel<<<BT / TM, 256, 0, stream>>>(z, eh, em, el, prec, out, codes_i);
    quant_kernel<<<BT / 256, 256, 0, stream>>>(z, cb, codes_i, out, partials);
    loss_kernel<<<1, 256, 0, stream>>>(partials, out);
}

// Round 11
// 115.457 us; speedup vs baseline: 1.4242x; 1.4242x over previous
//
#include <hip/hip_runtime.h>
#include <hip/hip_bf16.h>

typedef __attribute__((ext_vector_type(8))) short short8;   // 8 bf16 = 4 VGPR
typedef __attribute__((ext_vector_type(4))) float f32x4;

// Problem dims (fixed by reference)
constexpr int Bb = 8;
constexpr int Dd = 64;
constexpr int Tt = 8192;
constexpr int Kk = 1024;
constexpr int BT = Bb * Tt;            // 65536 rows
constexpr int NTOT = Bb * Dd * Tt;     // 4194304 elements

// Output layout (float32): [codes BT][quantized NTOT][loss 1]
constexpr int OUT_Q_OFF = BT;
constexpr int OUT_LOSS_OFF = BT + NTOT;

// Workspace layout (bytes)
constexpr size_t WS_CODES_OFF = 0;                        // int32[BT]      256KB
constexpr size_t WS_PREC_OFF  = (size_t)BT * 4;           // float[K]       4KB
constexpr size_t WS_PART_OFF  = WS_PREC_OFF + 4096;       // float[256]     1KB
constexpr size_t WS_EH_OFF    = WS_PART_OFF + 4096;       // bf16[K*D] x3
constexpr size_t WS_EM_OFF    = WS_EH_OFF + (size_t)Kk * Dd * 2;
constexpr size_t WS_EL_OFF    = WS_EM_OFF + (size_t)Kk * Dd * 2;

// ---- bf16 helpers (RNE, matches numpy/jax) ----
__device__ inline ushort rne_bf16(float v) {
    unsigned u = __float_as_uint(v);
    return (ushort)((u + 0x7FFFu + ((u >> 16) & 1u)) >> 16);
}
__device__ inline float bf16f(ushort h) { return __uint_as_float(((unsigned)h) << 16); }

// ---------------- Kernel PS: fused prec + 3-way bf16 split ----------------
__global__ void __launch_bounds__(256) prep_kernel(const float* __restrict__ cb,
                                                   float* __restrict__ prec,
                                                   ushort* __restrict__ eh,
                                                   ushort* __restrict__ em,
                                                   ushort* __restrict__ el) {
    const int k = blockIdx.x * 256 + threadIdx.x;   // grid = 4 blocks -> k in [0,1024)
    const float4* row = reinterpret_cast<const float4*>(cb + (size_t)k * Dd);
    float4 v[16];
    float s = 0.f;
#pragma unroll
    for (int i = 0; i < 16; ++i) {
        v[i] = row[i];
        s = fmaf(v[i].x, v[i].x, s); s = fmaf(v[i].y, v[i].y, s);
        s = fmaf(v[i].z, v[i].z, s); s = fmaf(v[i].w, v[i].w, s);
    }
    prec[k] = s;
#pragma unroll
    for (int g = 0; g < 8; ++g) {
        float vals[8] = {v[2*g].x, v[2*g].y, v[2*g].z, v[2*g].w,
                         v[2*g+1].x, v[2*g+1].y, v[2*g+1].z, v[2*g+1].w};
        short8 hv, mv, lv;
#pragma unroll
        for (int j = 0; j < 8; ++j) {
            float x = vals[j];
            ushort h = rne_bf16(x);  float hf = bf16f(h);
            float r1 = x - hf;       ushort m = rne_bf16(r1); float mf = bf16f(m);
            float r2 = r1 - mf;      ushort l = rne_bf16(r2);
            hv[j] = (short)h; mv[j] = (short)m; lv[j] = (short)l;
        }
        const size_t base = (size_t)k * 64 + g * 8;
        *reinterpret_cast<short8*>(eh + base) = hv;
        *reinterpret_cast<short8*>(em + base) = mv;
        *reinterpret_cast<short8*>(el + base) = lv;
    }
}

// ---------------- Kernel A: fused split-MFMA GEMM + argmin ----------------
// Numerics: 6-pass bf16 split MFMA (err ~1e-9), reference-order fp32 score
// s = fp32( fp32(zsq+esq) - 2*dot ), tie -> lowest k everywhere.
// Round-10 lesson: (256,3) with the 64rx16k wave tile spilled (demand ~210 >
// 170 budget: VGPR 84 + FETCH +17.5MB scratch). This version rebalances the
// wave tile to 32 rows x 32 k (2x2 wave grid): A 12 frags + B 12 frags + acc
// 16 + best 16 + zsq 8 ~= 150 regs -> fits 3 waves/SIMD without spill.
constexpr int TM = 64;              // rows per block
constexpr int NKT = Kk / 64;        // 16 k-tiles of 64 entries

__global__ void __launch_bounds__(256, 3) mfma_argmin_kernel(
    const float* __restrict__ z,
    const ushort* __restrict__ eh, const ushort* __restrict__ em,
    const ushort* __restrict__ el,
    const float* __restrict__ prec, float* __restrict__ out,
    int* __restrict__ codes_i)
{
    // z tile, 3 planes, swizzled: [split][row][d], row stride 128B, byte ^= (row&7)<<4
    __shared__ __align__(16) ushort z_lds[3 * 64 * 64];   // 24 KB
    __shared__ float zsq_part[4][64];
    __shared__ float zsq_lds[64];
    __shared__ float red_v[2][64];
    __shared__ int   red_i[2][64];

    const int tid = threadIdx.x;
    const int lane = tid & 63;
    const int w = tid >> 6;
    const int wr = w >> 1;                  // row half: rows wr*32..+32
    const int wk = w & 1;                   // k half within tile: wk*32..+32
    const int row0 = blockIdx.x * TM;
    const int b = row0 >> 13;
    const int t0 = row0 & (Tt - 1);

    // ---- stage z: read [d][t] coalesced, 3-way split, write transposed+swizzled
    {
        const int tt = tid & 63;            // row within tile
        const int dg = tid >> 6;            // d-group: d = dg*16 .. +16
        const float* zp = z + (size_t)b * (Dd * Tt) + (size_t)(dg * 16) * Tt + (t0 + tt);
        float vals[16];
        float psum = 0.f;
#pragma unroll
        for (int i = 0; i < 16; ++i) {
            float v = zp[(size_t)i * Tt];
            vals[i] = v;
            psum = fmaf(v, v, psum);
        }
        zsq_part[dg][tt] = psum;
#pragma unroll
        for (int g = 0; g < 2; ++g) {
            short8 hv, mv, lv;
#pragma unroll
            for (int j = 0; j < 8; ++j) {
                float v = vals[g * 8 + j];
                ushort h = rne_bf16(v);  float hf = bf16f(h);
                float r1 = v - hf;       ushort m = rne_bf16(r1); float mf = bf16f(m);
                float r2 = r1 - mf;      ushort l = rne_bf16(r2);
                hv[j] = (short)h; mv[j] = (short)m; lv[j] = (short)l;
            }
            const int byte_in_row = dg * 32 + g * 16;     // d0*2
            const int sw = tt * 128 + (byte_in_row ^ ((tt & 7) << 4));
            *reinterpret_cast<short8*>((char*)z_lds + 0 * 8192 + sw) = hv;
            *reinterpret_cast<short8*>((char*)z_lds + 1 * 8192 + sw) = mv;
            *reinterpret_cast<short8*>((char*)z_lds + 2 * 8192 + sw) = lv;
        }
    }
    __syncthreads();
    if (tid < 64)
        zsq_lds[tid] = ((zsq_part[0][tid] + zsq_part[1][tid]) + zsq_part[2][tid]) + zsq_part[3][tid];
    __syncthreads();

    // ---- A fragments into registers (once): [plane][ds][rf], rf in {0,1}
    short8 A[3][2][2];
#pragma unroll
    for (int sA = 0; sA < 3; ++sA)
#pragma unroll
        for (int ds = 0; ds < 2; ++ds)
#pragma unroll
            for (int rf = 0; rf < 2; ++rf) {
                const int row = wr * 32 + rf * 16 + (lane & 15);
                const int dby = ds * 64 + ((lane >> 4) * 16);
                A[sA][ds][rf] = *reinterpret_cast<const short8*>(
                    (char*)z_lds + sA * 8192 + row * 128 + (dby ^ ((row & 7) << 4)));
            }

    // per-lane row-set zsq: row = wr*32 + rf*16 + (lane>>4)*4 + j
    float zsq_r[8];
#pragma unroll
    for (int rf = 0; rf < 2; ++rf)
#pragma unroll
        for (int j = 0; j < 4; ++j)
            zsq_r[rf * 4 + j] = zsq_lds[wr * 32 + rf * 16 + (lane >> 4) * 4 + j];

    float bestv[8];
    int   besti[8];
#pragma unroll
    for (int i = 0; i < 8; ++i) { bestv[i] = 3.4e38f; besti[i] = 0; }

    const int kl = lane & 15;
    const int d16 = lane >> 4;
    // per-lane byte offset within a plane for tile 0 (ds0, kf0):
    // bytes = wk*4096 + kl*128 + d16*16 ; per-tile advance = 64*64*2 = 8192
    int voff = wk * 4096 + kl * 128 + d16 * 16;
    int eoff = (wk * 32 + kl) * 4;          // prec bytes; kf1 = +64B; +256B/tile

    for (int kt = 0; kt < NKT; ++kt) {
        const char* peh = (const char*)eh + voff;
        const char* pem = (const char*)em + voff;
        const char* pel = (const char*)el + voff;
        // B frags: [ds][kf]; imm = kf*2048 + ds*64
        short8 Bh[2][2], Bm[2][2], Bl[2][2];
        Bh[0][0] = *reinterpret_cast<const short8*>(peh + 0);
        Bh[1][0] = *reinterpret_cast<const short8*>(peh + 64);
        Bh[0][1] = *reinterpret_cast<const short8*>(peh + 2048);
        Bh[1][1] = *reinterpret_cast<const short8*>(peh + 2112);
        Bm[0][0] = *reinterpret_cast<const short8*>(pem + 0);
        Bm[1][0] = *reinterpret_cast<const short8*>(pem + 64);
        Bm[0][1] = *reinterpret_cast<const short8*>(pem + 2048);
        Bm[1][1] = *reinterpret_cast<const short8*>(pem + 2112);
        Bl[0][0] = *reinterpret_cast<const short8*>(pel + 0);
        Bl[1][0] = *reinterpret_cast<const short8*>(pel + 64);
        Bl[0][1] = *reinterpret_cast<const short8*>(pel + 2048);
        Bl[1][1] = *reinterpret_cast<const short8*>(pel + 2112);
        const float esq0 = *reinterpret_cast<const float*>((const char*)prec + eoff);
        const float esq1 = *reinterpret_cast<const float*>((const char*)prec + eoff + 64);

        f32x4 acc[2][2];
#pragma unroll
        for (int rf = 0; rf < 2; ++rf)
#pragma unroll
            for (int kf = 0; kf < 2; ++kf) acc[rf][kf] = (f32x4){0.f, 0.f, 0.f, 0.f};

        // eh-planes first (prefetch-free latency cover for em/el loads)
#pragma unroll
        for (int ds = 0; ds < 2; ++ds) {
#pragma unroll
            for (int rf = 0; rf < 2; ++rf)
#pragma unroll
                for (int kf = 0; kf < 2; ++kf)
                    acc[rf][kf] = __builtin_amdgcn_mfma_f32_16x16x32_bf16(A[0][ds][rf], Bh[ds][kf], acc[rf][kf], 0, 0, 0);
#pragma unroll
            for (int rf = 0; rf < 2; ++rf)
#pragma unroll
                for (int kf = 0; kf < 2; ++kf)
                    acc[rf][kf] = __builtin_amdgcn_mfma_f32_16x16x32_bf16(A[1][ds][rf], Bh[ds][kf], acc[rf][kf], 0, 0, 0);
#pragma unroll
            for (int rf = 0; rf < 2; ++rf)
#pragma unroll
                for (int kf = 0; kf < 2; ++kf)
                    acc[rf][kf] = __builtin_amdgcn_mfma_f32_16x16x32_bf16(A[2][ds][rf], Bh[ds][kf], acc[rf][kf], 0, 0, 0);
#pragma unroll
            for (int rf = 0; rf < 2; ++rf)
#pragma unroll
                for (int kf = 0; kf < 2; ++kf)
                    acc[rf][kf] = __builtin_amdgcn_mfma_f32_16x16x32_bf16(A[0][ds][rf], Bm[ds][kf], acc[rf][kf], 0, 0, 0);
#pragma unroll
            for (int rf = 0; rf < 2; ++rf)
#pragma unroll
                for (int kf = 0; kf < 2; ++kf)
                    acc[rf][kf] = __builtin_amdgcn_mfma_f32_16x16x32_bf16(A[1][ds][rf], Bm[ds][kf], acc[rf][kf], 0, 0, 0);
#pragma unroll
            for (int rf = 0; rf < 2; ++rf)
#pragma unroll
                for (int kf = 0; kf < 2; ++kf)
                    acc[rf][kf] = __builtin_amdgcn_mfma_f32_16x16x32_bf16(A[0][ds][rf], Bl[ds][kf], acc[rf][kf], 0, 0, 0);
        }

        // epilogue: score, in-lane min over kf (kf0 = lower k, strict <),
        // then running min (strict < keeps earlier=lower k on ties)
        const int kbase = kt * 64 + wk * 32 + kl;
#pragma unroll
        for (int rf = 0; rf < 2; ++rf)
#pragma unroll
            for (int j = 0; j < 4; ++j) {
                const float zr = zsq_r[rf * 4 + j];
                const float s0v = fmaf(-2.f, acc[rf][0][j], zr + esq0);
                const float s1v = fmaf(-2.f, acc[rf][1][j], zr + esq1);
                float cv; int ci;
                if (s1v < s0v) { cv = s1v; ci = kbase + 16; }
                else           { cv = s0v; ci = kbase; }
                const int slot = rf * 4 + j;
                if (cv < bestv[slot]) { bestv[slot] = cv; besti[slot] = ci; }
            }

        voff += 8192;
        eoff += 256;
    }

    // ---- in-wave reduce over the 16 kl slots per row, tie -> lower k
#pragma unroll
    for (int i = 0; i < 8; ++i) {
#pragma unroll
        for (int m = 1; m < 16; m <<= 1) {
            const float ov = __shfl_xor(bestv[i], m, 16);
            const int   oi = __shfl_xor(besti[i], m, 16);
            if (ov < bestv[i] || (ov == bestv[i] && oi < besti[i])) {
                bestv[i] = ov; besti[i] = oi;
            }
        }
    }
    if (kl == 0) {
#pragma unroll
        for (int rf = 0; rf < 2; ++rf)
#pragma unroll
            for (int j = 0; j < 4; ++j) {
                const int row_local = wr * 32 + rf * 16 + d16 * 4 + j;
                red_v[wk][row_local] = bestv[rf * 4 + j];
                red_i[wk][row_local] = besti[rf * 4 + j];
            }
    }
    __syncthreads();
    if (tid < 64) {
        float bv = red_v[0][tid];
        int   bi = red_i[0][tid];
        const float v1 = red_v[1][tid];
        const int   i1 = red_i[1][tid];
        if (v1 < bv || (v1 == bv && i1 < bi)) { bv = v1; bi = i1; }
        codes_i[row0 + tid] = bi;
        out[row0 + tid] = (float)bi;
    }
}

// ---------------- Kernel B: quantized + loss partials ----------------
__global__ void __launch_bounds__(256) quant_kernel(
    const float* __restrict__ z, const float* __restrict__ cb,
    const int* __restrict__ codes_i, float* __restrict__ out,
    float* __restrict__ partials)
{
    const int row = blockIdx.x * 256 + threadIdx.x;  // grid = 256 blocks
    const int b = row >> 13;
    const int t = row & (Tt - 1);
    const int code = codes_i[row];
    const float4* crow = reinterpret_cast<const float4*>(cb + (size_t)code * Dd);
    const float* zbase = z + (size_t)b * (Dd * Tt) + t;
    float* obase = out + OUT_Q_OFF + (size_t)b * (Dd * Tt) + t;

    float acc = 0.f;
#pragma unroll
    for (int d4 = 0; d4 < 16; ++d4) {
        float4 v = crow[d4];
        float vv[4] = {v.x, v.y, v.z, v.w};
#pragma unroll
        for (int j = 0; j < 4; ++j) {
            const int d = d4 * 4 + j;
            const float zv = zbase[(size_t)d * Tt];
            const float diff = vv[j] - zv;
            acc = fmaf(diff, diff, acc);
            obase[(size_t)d * Tt] = vv[j];
        }
    }

    __shared__ float red[256];
    red[threadIdx.x] = acc;
    __syncthreads();
#pragma unroll
    for (int s = 128; s > 0; s >>= 1) {
        if (threadIdx.x < s) red[threadIdx.x] += red[threadIdx.x + s];
        __syncthreads();
    }
    if (threadIdx.x == 0) partials[blockIdx.x] = red[0];
}

// ---------------- Kernel C: final loss reduce ----------------
__global__ void __launch_bounds__(256) loss_kernel(const float* __restrict__ partials,
                                                   float* __restrict__ out) {
    __shared__ float red[256];
    red[threadIdx.x] = partials[threadIdx.x];  // exactly 256 partials
    __syncthreads();
#pragma unroll
    for (int s = 128; s > 0; s >>= 1) {
        if (threadIdx.x < s) red[threadIdx.x] += red[threadIdx.x + s];
        __syncthreads();
    }
    if (threadIdx.x == 0)
        out[OUT_LOSS_OFF] = red[0] * (1.0f / (float)NTOT);
}

extern "C" void kernel_launch(void* const* d_in, const int* in_sizes, int n_in,
                              void* d_out, int out_size, void* d_ws, size_t ws_size,
                              hipStream_t stream) {
    const float* z = (const float*)d_in[0];
    const float* cb = (const float*)d_in[1];
    float* out = (float*)d_out;

    char* ws = (char*)d_ws;
    int* codes_i = (int*)(ws + WS_CODES_OFF);
    float* prec = (float*)(ws + WS_PREC_OFF);
    float* partials = (float*)(ws + WS_PART_OFF);
    ushort* eh = (ushort*)(ws + WS_EH_OFF);
    ushort* em = (ushort*)(ws + WS_EM_OFF);
    ushort* el = (ushort*)(ws + WS_EL_OFF);

    prep_kernel<<<Kk / 256, 256, 0, stream>>>(cb, prec, eh, em, el);
    mfma_argmin_kernel<<<BT / TM, 256, 0, stream>>>(z, eh, em, el, prec, out, codes_i);
    quant_kernel<<<BT / 256, 256, 0, stream>>>(z, cb, codes_i, out, partials);
    loss_kernel<<<1, 256, 0, stream>>>(partials, out);
}